// Round 3
// baseline (1283.849 us; speedup 1.0000x reference)
//
#include <hip/hip_runtime.h>

#define NEDGES 1600000
#define NNODES 100000
#define NF 128
#define NSCAN_BLK 98   // ceil(100000/1024)

typedef short s16x8 __attribute__((ext_vector_type(8)));
typedef float f32x4 __attribute__((ext_vector_type(4)));

// ---- workspace byte layout ----
#define CNT_B    0u         // int[100000]
#define ROWPTR_B 400000u    // int[100001]
#define CURSOR_B 800016u    // int[100000]
#define EIDS_B   1200016u   // uint[1600000]  packed (eid<<4)|(dst&15)
#define WBF_B    7600016u   // ushort[16384]
#define BSUM_B   7632784u   // int[98]
#define BSUMX_B  7633176u   // int[98]

static __device__ __forceinline__ unsigned short f2bf(float x) {
    unsigned u = __float_as_uint(x);
    return (unsigned short)((u + 0x7fffu + ((u >> 16) & 1u)) >> 16);  // RNE
}

__global__ __launch_bounds__(256) void k_hist(const int* __restrict__ dst,
                                              int* __restrict__ cnt) {
    int i = blockIdx.x * 256 + threadIdx.x;
    if (i < NEDGES) atomicAdd(&cnt[dst[i]], 1);
}

// Coalesced scan, pass 1: per-block (1024-wide) exclusive scan of cnt.
__global__ __launch_bounds__(1024) void k_scan1(const int* __restrict__ cnt,
                                                int* __restrict__ rowptr,
                                                int* __restrict__ bsum) {
    const int t = threadIdx.x;
    const int i = blockIdx.x * 1024 + t;
    const int v = (i < NNODES) ? cnt[i] : 0;
    __shared__ int ps[1024];
    ps[t] = v;
    __syncthreads();
    for (int off = 1; off < 1024; off <<= 1) {
        int u = (t >= off) ? ps[t - off] : 0;
        __syncthreads();
        ps[t] += u;
        __syncthreads();
    }
    if (i < NNODES) rowptr[i] = ps[t] - v;           // local exclusive
    if (t == 1023) bsum[blockIdx.x] = ps[1023];      // block total
}

// Pass 2: exclusive scan of the 98 block sums (single tiny block).
__global__ __launch_bounds__(128) void k_scan2(const int* __restrict__ bsum,
                                               int* __restrict__ bsumx) {
    const int t = threadIdx.x;
    const int v = (t < NSCAN_BLK) ? bsum[t] : 0;
    __shared__ int ps[128];
    ps[t] = v;
    __syncthreads();
    for (int off = 1; off < 128; off <<= 1) {
        int u = (t >= off) ? ps[t - off] : 0;
        __syncthreads();
        ps[t] += u;
        __syncthreads();
    }
    if (t < NSCAN_BLK) bsumx[t] = ps[t] - v;
}

// Pass 3: add block offsets; produce final rowptr + cursor copy + sentinel.
__global__ __launch_bounds__(1024) void k_scan3(int* __restrict__ rowptr,
                                                const int* __restrict__ bsumx,
                                                int* __restrict__ cursor) {
    const int i = blockIdx.x * 1024 + threadIdx.x;
    if (i < NNODES) {
        const int r = rowptr[i] + bsumx[blockIdx.x];
        rowptr[i] = r;
        cursor[i] = r;
    }
    if (i == 0) rowptr[NNODES] = NEDGES;
}

// Fill CSR edge list; value packs edge id + local row within its 16-node tile.
__global__ __launch_bounds__(256) void k_fill(const int* __restrict__ dst,
                                              int* __restrict__ cursor,
                                              unsigned* __restrict__ eids) {
    int i = blockIdx.x * 256 + threadIdx.x;
    if (i < NEDGES) {
        const int d = dst[i];
        const int p = atomicAdd(&cursor[d], 1);
        eids[p] = ((unsigned)i << 4) | (unsigned)(d & 15);
    }
}

__global__ __launch_bounds__(256) void k_wconv(const float* __restrict__ W,
                                               unsigned short* __restrict__ Wb) {
    int i = blockIdx.x * 256 + threadIdx.x;
    if (i < NF * NF) Wb[i] = f2bf(W[i]);
}

// ---------------------------------------------------------------------------
// Fused gather + mean + (W @ agg + b) + ReLU.  One block = one 16-node tile.
// Phase 1 (edge-parallel): the tile's edge list is contiguous in eids; all 4
//   waves stride it 8-deep. Lane handles feats (2l, 2l+1) via one 8B nt load.
//   Accumulate f32 in LDS via ds_add_f32; layout x->col lane, y->col 64+lane
//   with row stride 132 => bank (4r+lane)%32, 2 lanes/bank = conflict-free.
// Phase 2: 256 threads convert/mean/pack to the swizzled bf16 tile
//   (byte = (row*256 + pair*4) ^ ((row&7)<<4), verified in R2).
// Phase 3: per-wave 2 j-tiles of mfma_f32_16x16x32_bf16, K=128; W fragments
//   loaded from L2-hot Wb after the gather (keeps gather-phase VGPRs low).
// ---------------------------------------------------------------------------
__global__ __launch_bounds__(256) void k_fused(
        const float* __restrict__ edge, const int* __restrict__ rowptr,
        const unsigned* __restrict__ eids, const unsigned short* __restrict__ Wb,
        const float* __restrict__ bias, float* __restrict__ out) {
    __shared__ float aggf[16][132];               // 8448 B, padded stride
    __shared__ __align__(16) char aggb[16 * 256]; // swizzled bf16 tile
    const int tid  = threadIdx.x;
    const int lane = tid & 63;
    const int wv   = tid >> 6;
    const int l15  = lane & 15;
    const int l4   = lane >> 4;
    const int n0   = blockIdx.x * 16;

    for (int idx = tid; idx < 16 * 132; idx += 256)
        (&aggf[0][0])[idx] = 0.0f;
    __syncthreads();

    const int eb = rowptr[n0];
    const int ee = rowptr[n0 + 16];

    for (int e0 = eb + wv * 8; e0 < ee; e0 += 32) {
        float2 xs[8];
        int    lrs[8];
        #pragma unroll
        for (int j = 0; j < 8; ++j) {
            const int ec = min(e0 + j, ee - 1);       // clamp (tail-safe)
            const unsigned v = eids[ec];
            lrs[j] = (int)(v & 15u);
            const double dv = __builtin_nontemporal_load(
                (const double*)(edge + (size_t)(v >> 4) * NF + lane * 2));
            __builtin_memcpy(&xs[j], &dv, 8);
        }
        #pragma unroll
        for (int j = 0; j < 8; ++j) {
            if (e0 + j < ee) {
                atomicAdd(&aggf[lrs[j]][lane], xs[j].x);
                atomicAdd(&aggf[lrs[j]][64 + lane], xs[j].y);
            }
        }
    }
    __syncthreads();

    // Phase 2: mean + bf16 pack. Thread t: row r=t>>4, pairs p0..p0+3.
    {
        const int r  = tid >> 4;
        const int p0 = (tid & 15) * 4;
        const int cs = rowptr[n0 + r];
        const int ce = rowptr[n0 + r + 1];
        const float inv = 1.0f / fmaxf((float)(ce - cs), 1.0f);
        const float4 xv = *(const float4*)&aggf[r][p0];       // x of lanes p0..p0+3
        const float4 yv = *(const float4*)&aggf[r][64 + p0];  // y of lanes p0..p0+3
        const float xa[4] = {xv.x, xv.y, xv.z, xv.w};
        const float ya[4] = {yv.x, yv.y, yv.z, yv.w};
        #pragma unroll
        for (int j = 0; j < 4; ++j) {
            const unsigned pk = (unsigned)f2bf(xa[j] * inv) |
                                ((unsigned)f2bf(ya[j] * inv) << 16);
            const int byt = ((r * 256 + (p0 + j) * 4) ^ ((r & 7) << 4));
            *(unsigned*)(aggb + byt) = pk;
        }
    }
    __syncthreads();

    // Phase 3: MFMA. B[k][n] = W[j0+n][k]; lane -> n=l15, k=l4*8..+8.
    #pragma unroll
    for (int t = 0; t < 2; ++t) {
        const int j0 = (wv * 2 + t) * 16;
        f32x4 acc = {0.f, 0.f, 0.f, 0.f};
        #pragma unroll
        for (int ks = 0; ks < 4; ++ks) {
            const s16x8 wfv = *(const s16x8*)((const char*)Wb +
                                              (j0 + l15) * 256 + ks * 64 + l4 * 16);
            const int byt = ((l15 * 256 + ks * 64 + l4 * 16) ^ ((l15 & 7) << 4));
            const s16x8 av = *(const s16x8*)(aggb + byt);
            acc = __builtin_amdgcn_mfma_f32_16x16x32_bf16(av, wfv, acc, 0, 0, 0);
        }
        const float bj = bias[j0 + l15];
        #pragma unroll
        for (int r = 0; r < 4; ++r) {
            const int m = l4 * 4 + r;
            out[(size_t)(n0 + m) * NF + j0 + l15] = fmaxf(acc[r] + bj, 0.f);
        }
    }
}

extern "C" void kernel_launch(void* const* d_in, const int* in_sizes, int n_in,
                              void* d_out, int out_size, void* d_ws, size_t ws_size,
                              hipStream_t stream) {
    const float* edge = (const float*)d_in[0];
    const int*   dst  = (const int*)d_in[1];
    const float* W    = (const float*)d_in[2];
    const float* b    = (const float*)d_in[3];
    float* out = (float*)d_out;

    char* ws = (char*)d_ws;
    int*            cnt    = (int*)(ws + CNT_B);
    int*            rowptr = (int*)(ws + ROWPTR_B);
    int*            cursor = (int*)(ws + CURSOR_B);
    unsigned*       eids   = (unsigned*)(ws + EIDS_B);
    unsigned short* Wb     = (unsigned short*)(ws + WBF_B);
    int*            bsum   = (int*)(ws + BSUM_B);
    int*            bsumx  = (int*)(ws + BSUMX_B);

    hipMemsetAsync(cnt, 0, (size_t)NNODES * sizeof(int), stream);

    k_wconv<<<(NF * NF + 255) / 256, 256, 0, stream>>>(W, Wb);
    k_hist<<<(NEDGES + 255) / 256, 256, 0, stream>>>(dst, cnt);
    k_scan1<<<NSCAN_BLK, 1024, 0, stream>>>(cnt, rowptr, bsum);
    k_scan2<<<1, 128, 0, stream>>>(bsum, bsumx);
    k_scan3<<<NSCAN_BLK, 1024, 0, stream>>>(rowptr, bsumx, cursor);
    k_fill<<<(NEDGES + 255) / 256, 256, 0, stream>>>(dst, cursor, eids);
    k_fused<<<NNODES / 16, 256, 0, stream>>>(edge, rowptr, eids, Wb, b, out);
}

// Round 4
// 399.480 us; speedup vs baseline: 3.2138x; 3.2138x over previous
//
#include <hip/hip_runtime.h>

#define NEDGES 1600000
#define NNODES 100000
#define NF 128
#define NSCAN_BLK 98   // ceil(100000/1024)

typedef short s16x8 __attribute__((ext_vector_type(8)));
typedef float f32x4 __attribute__((ext_vector_type(4)));

// ---- workspace byte layout ----
#define CNT_B    0u         // int[100000]
#define ROWPTR_B 400000u    // int[100001]
#define CURSOR_B 800016u    // int[100000]
#define EIDS_B   1200016u   // uint[1600000]  packed (eid<<4)|(dst&15)
#define WBF_B    7600016u   // ushort[16384]
#define BSUM_B   7632784u   // int[98]
#define BSUMX_B  7633176u   // int[98]

static __device__ __forceinline__ unsigned short f2bf(float x) {
    unsigned u = __float_as_uint(x);
    return (unsigned short)((u + 0x7fffu + ((u >> 16) & 1u)) >> 16);  // RNE
}

__global__ __launch_bounds__(256) void k_hist(const int* __restrict__ dst,
                                              int* __restrict__ cnt) {
    int i = blockIdx.x * 256 + threadIdx.x;
    if (i < NEDGES) atomicAdd(&cnt[dst[i]], 1);
}

__global__ __launch_bounds__(1024) void k_scan1(const int* __restrict__ cnt,
                                                int* __restrict__ rowptr,
                                                int* __restrict__ bsum) {
    const int t = threadIdx.x;
    const int i = blockIdx.x * 1024 + t;
    const int v = (i < NNODES) ? cnt[i] : 0;
    __shared__ int ps[1024];
    ps[t] = v;
    __syncthreads();
    for (int off = 1; off < 1024; off <<= 1) {
        int u = (t >= off) ? ps[t - off] : 0;
        __syncthreads();
        ps[t] += u;
        __syncthreads();
    }
    if (i < NNODES) rowptr[i] = ps[t] - v;
    if (t == 1023) bsum[blockIdx.x] = ps[1023];
}

__global__ __launch_bounds__(128) void k_scan2(const int* __restrict__ bsum,
                                               int* __restrict__ bsumx) {
    const int t = threadIdx.x;
    const int v = (t < NSCAN_BLK) ? bsum[t] : 0;
    __shared__ int ps[128];
    ps[t] = v;
    __syncthreads();
    for (int off = 1; off < 128; off <<= 1) {
        int u = (t >= off) ? ps[t - off] : 0;
        __syncthreads();
        ps[t] += u;
        __syncthreads();
    }
    if (t < NSCAN_BLK) bsumx[t] = ps[t] - v;
}

__global__ __launch_bounds__(1024) void k_scan3(int* __restrict__ rowptr,
                                                const int* __restrict__ bsumx,
                                                int* __restrict__ cursor) {
    const int i = blockIdx.x * 1024 + threadIdx.x;
    if (i < NNODES) {
        const int r = rowptr[i] + bsumx[blockIdx.x];
        rowptr[i] = r;
        cursor[i] = r;
    }
    if (i == 0) rowptr[NNODES] = NEDGES;
}

__global__ __launch_bounds__(256) void k_fill(const int* __restrict__ dst,
                                              int* __restrict__ cursor,
                                              unsigned* __restrict__ eids) {
    int i = blockIdx.x * 256 + threadIdx.x;
    if (i < NEDGES) {
        const int d = dst[i];
        const int p = atomicAdd(&cursor[d], 1);
        eids[p] = ((unsigned)i << 4) | (unsigned)(d & 15);
    }
}

__global__ __launch_bounds__(256) void k_wconv(const float* __restrict__ W,
                                               unsigned short* __restrict__ Wb) {
    int i = blockIdx.x * 256 + threadIdx.x;
    if (i < NF * NF) Wb[i] = f2bf(W[i]);
}

// ---------------------------------------------------------------------------
// Fused gather + mean + (W @ agg + b) + ReLU.  One block = one 16-node tile.
// Gather (R4): block's edge list [eb,ee) is split into 4 contiguous per-wave
//   chunks (perfect balance). Per 64-edge sub-chunk: ONE coalesced lane-load
//   of eids (eids[base+lane]), then ids broadcast via v_readlane (SGPR) — no
//   pointer-chase, no per-edge eids latency. Full batches of 8 issue 8
//   unconditional independent 512B edge loads (float2/lane), then segmented
//   REGISTER accumulation: CSR order => row changes ~once per 16 edges; on
//   change, flush (a0,a1) to LDS f32 tile via atomicAdd (conflict-free banks:
//   word addr = 132*row + lane -> 2 lanes/bank).
// Phase 2: mean + bf16 pack into XOR-swizzled tile (byte ^= (row&7)<<4).
// Phase 3: per-wave 2 j-tiles of mfma_f32_16x16x32_bf16, K=128.
//   D layout: col = lane&15, row = (lane>>4)*4 + reg (verified m89/R2).
// ---------------------------------------------------------------------------
__global__ __launch_bounds__(256) void k_fused(
        const float* __restrict__ edge, const int* __restrict__ rowptr,
        const unsigned* __restrict__ eids, const unsigned short* __restrict__ Wb,
        const float* __restrict__ bias, float* __restrict__ out) {
    __shared__ float aggf[16][132];
    __shared__ __align__(16) char aggb[16 * 256];
    const int tid  = threadIdx.x;
    const int lane = tid & 63;
    const int wv   = tid >> 6;
    const int l15  = lane & 15;
    const int l4   = lane >> 4;
    const int n0   = blockIdx.x * 16;

    for (int idx = tid; idx < 16 * 132; idx += 256)
        (&aggf[0][0])[idx] = 0.0f;
    __syncthreads();

    const int eb    = rowptr[n0];
    const int ee    = rowptr[n0 + 16];
    const int chunk = (ee - eb + 3) >> 2;
    const int ws    = eb + wv * chunk;
    const int we    = min(ws + chunk, ee);

    int   cur = -1;
    float a0 = 0.f, a1 = 0.f;

    for (int base = ws; base < we; base += 64) {
        const int m = min(64, we - base);
        const unsigned ev = (lane < m) ? eids[base + lane] : 0u;
        int b = 0;
        for (; b + 8 <= m; b += 8) {
            unsigned id[8];
            int      rw[8];
            #pragma unroll
            for (int j = 0; j < 8; ++j) {
                const unsigned u = (unsigned)__builtin_amdgcn_readlane((int)ev, b + j);
                id[j] = u >> 4;
                rw[j] = (int)(u & 15u);
            }
            float2 xv[8];
            #pragma unroll
            for (int j = 0; j < 8; ++j)
                xv[j] = *(const float2*)(edge + (size_t)id[j] * NF + lane * 2);
            #pragma unroll
            for (int j = 0; j < 8; ++j) {
                if (rw[j] != cur) {            // wave-uniform scalar branch
                    if (cur >= 0) {
                        atomicAdd(&aggf[cur][lane], a0);
                        atomicAdd(&aggf[cur][64 + lane], a1);
                    }
                    cur = rw[j];
                    a0 = 0.f; a1 = 0.f;
                }
                a0 += xv[j].x;
                a1 += xv[j].y;
            }
        }
        for (; b < m; ++b) {
            const unsigned u = (unsigned)__builtin_amdgcn_readlane((int)ev, b);
            const float2 v = *(const float2*)(edge + (size_t)(u >> 4) * NF + lane * 2);
            const int r = (int)(u & 15u);
            if (r != cur) {
                if (cur >= 0) {
                    atomicAdd(&aggf[cur][lane], a0);
                    atomicAdd(&aggf[cur][64 + lane], a1);
                }
                cur = r;
                a0 = 0.f; a1 = 0.f;
            }
            a0 += v.x;
            a1 += v.y;
        }
    }
    if (cur >= 0) {
        atomicAdd(&aggf[cur][lane], a0);
        atomicAdd(&aggf[cur][64 + lane], a1);
    }
    __syncthreads();

    // Phase 2: mean + bf16 pack. Thread t: row r=t>>4, feature-pairs p0..p0+3.
    {
        const int r  = tid >> 4;
        const int p0 = (tid & 15) * 4;
        const int cs = rowptr[n0 + r];
        const int ce = rowptr[n0 + r + 1];
        const float inv = 1.0f / fmaxf((float)(ce - cs), 1.0f);
        const float4 xv = *(const float4*)&aggf[r][p0];
        const float4 yv = *(const float4*)&aggf[r][64 + p0];
        const float xa[4] = {xv.x, xv.y, xv.z, xv.w};
        const float ya[4] = {yv.x, yv.y, yv.z, yv.w};
        #pragma unroll
        for (int j = 0; j < 4; ++j) {
            const unsigned pk = (unsigned)f2bf(xa[j] * inv) |
                                ((unsigned)f2bf(ya[j] * inv) << 16);
            const int byt = ((r * 256 + (p0 + j) * 4) ^ ((r & 7) << 4));
            *(unsigned*)(aggb + byt) = pk;
        }
    }
    __syncthreads();

    // Phase 3: MFMA. B[k][n] = W[j0+n][k]; lane -> n=l15, k=l4*8..+8.
    #pragma unroll
    for (int t = 0; t < 2; ++t) {
        const int j0 = (wv * 2 + t) * 16;
        f32x4 acc = {0.f, 0.f, 0.f, 0.f};
        #pragma unroll
        for (int ks = 0; ks < 4; ++ks) {
            const s16x8 wfv = *(const s16x8*)((const char*)Wb +
                                              (j0 + l15) * 256 + ks * 64 + l4 * 16);
            const int byt = ((l15 * 256 + ks * 64 + l4 * 16) ^ ((l15 & 7) << 4));
            const s16x8 av = *(const s16x8*)(aggb + byt);
            acc = __builtin_amdgcn_mfma_f32_16x16x32_bf16(av, wfv, acc, 0, 0, 0);
        }
        const float bj = bias[j0 + l15];
        #pragma unroll
        for (int r = 0; r < 4; ++r) {
            const int m = l4 * 4 + r;
            out[(size_t)(n0 + m) * NF + j0 + l15] = fmaxf(acc[r] + bj, 0.f);
        }
    }
}

extern "C" void kernel_launch(void* const* d_in, const int* in_sizes, int n_in,
                              void* d_out, int out_size, void* d_ws, size_t ws_size,
                              hipStream_t stream) {
    const float* edge = (const float*)d_in[0];
    const int*   dst  = (const int*)d_in[1];
    const float* W    = (const float*)d_in[2];
    const float* b    = (const float*)d_in[3];
    float* out = (float*)d_out;

    char* ws = (char*)d_ws;
    int*            cnt    = (int*)(ws + CNT_B);
    int*            rowptr = (int*)(ws + ROWPTR_B);
    int*            cursor = (int*)(ws + CURSOR_B);
    unsigned*       eids   = (unsigned*)(ws + EIDS_B);
    unsigned short* Wb     = (unsigned short*)(ws + WBF_B);
    int*            bsum   = (int*)(ws + BSUM_B);
    int*            bsumx  = (int*)(ws + BSUMX_B);

    hipMemsetAsync(cnt, 0, (size_t)NNODES * sizeof(int), stream);

    k_wconv<<<(NF * NF + 255) / 256, 256, 0, stream>>>(W, Wb);
    k_hist<<<(NEDGES + 255) / 256, 256, 0, stream>>>(dst, cnt);
    k_scan1<<<NSCAN_BLK, 1024, 0, stream>>>(cnt, rowptr, bsum);
    k_scan2<<<1, 128, 0, stream>>>(bsum, bsumx);
    k_scan3<<<NSCAN_BLK, 1024, 0, stream>>>(rowptr, bsumx, cursor);
    k_fill<<<(NEDGES + 255) / 256, 256, 0, stream>>>(dst, cursor, eids);
    k_fused<<<NNODES / 16, 256, 0, stream>>>(edge, rowptr, eids, Wb, b, out);
}